// Round 3
// baseline (820.204 us; speedup 1.0000x reference)
//
#include <hip/hip_runtime.h>
#include <math.h>

// GNN message-passing layer — linearity-exploiting restructure.
// msg = [x_snd|e_attr] @ Wm^T is LINEAR, so
//   agg[r] = (sum_{e->r} x_snd) @ Wm_x^T + (sum e_attr) @ Wm_e^T
// Pipeline:
//   counts=0; hist(receivers); scan -> row_ptr/cursor; build -> perm/snds (CSR)
//   aggsum: S[r][0:128] = sum nodes[snd], S[r][128:160] = sum eattr   (fp32, NO atomics)
//   wcat:   Wcat = [W1[:, :128] | W1[:,128:] @ Wm]  (fold agg GEMM into node GEMM 1)
//   node<288,0>: h        = LN(relu([nodes|S] @ Wcat^T + b1))
//   node<128,1>: node_out = LN(relu(h @ W2^T + b2))
//   node<128,2>: out      = LN(nodes @ Wn^T + node_out)
// GEMMs: fp32 global -> bf16 LDS -> v_mfma_f32_16x16x32_bf16, fp32 acc.
// Block tile M=64 x N=128, BK=32, 4 waves 2x2, each wave 32x64 (2x4 16x16 tiles).

#define THREADS 256
#define BM 64
#define BK 32
#define APB 40   // LDS row pitch in bf16
#define BP 132   // Cs row pitch (floats)

typedef __attribute__((ext_vector_type(8))) short bf16x8;
typedef __attribute__((ext_vector_type(4))) float f32x4;

struct GemmSmem {
  unsigned short As[BM][APB];
  unsigned short Bs[128][APB];
};
struct EpiSmem {
  float Cs[BM][BP];
  float psum[BM][4];
  float psq[BM][4];
  float mu[BM];
  float rs[BM];
};
union NodeSmem {
  GemmSmem g;
  EpiSmem e;
};

__device__ __forceinline__ unsigned short f2bf(float x) {
  union { float f; unsigned u; } c;
  c.f = x;
  unsigned u = c.u;
  u += 0x7fffu + ((u >> 16) & 1u);
  return (unsigned short)(u >> 16);
}

__device__ __forceinline__ void store_bf4(unsigned short* dst, float4 v) {
  ushort4 p;
  p.x = f2bf(v.x); p.y = f2bf(v.y); p.z = f2bf(v.z); p.w = f2bf(v.w);
  *(ushort4*)dst = p;
}

template <int KT>
__device__ __forceinline__ void load_B(GemmSmem& sm, const float* __restrict__ W,
                                       int kc, int tid) {
#pragma unroll
  for (int c = 0; c < 4; ++c) {
    int f = tid + THREADS * c;   // float4 index in [128][8]
    int n = f >> 3, u = f & 7;
    float4 v = *(const float4*)&W[(size_t)n * KT + kc + 4 * u];
    store_bf4(&sm.Bs[n][4 * u], v);
  }
}

__device__ __forceinline__ void gemm_chunk(const GemmSmem& sm, int tid,
                                           f32x4 acc[2][4]) {
  const int lane = tid & 63;
  const int quad = lane >> 4;
  const int lm = lane & 15;
  const int wid = tid >> 6;
  const int wy = wid >> 1, wx = wid & 1;

  bf16x8 af[2], bf[4];
#pragma unroll
  for (int mt = 0; mt < 2; ++mt)
    af[mt] = *(const bf16x8*)&sm.As[32 * wy + 16 * mt + lm][quad * 8];
#pragma unroll
  for (int nt = 0; nt < 4; ++nt)
    bf[nt] = *(const bf16x8*)&sm.Bs[64 * wx + 16 * nt + lm][quad * 8];
#pragma unroll
  for (int mt = 0; mt < 2; ++mt)
#pragma unroll
    for (int nt = 0; nt < 4; ++nt)
      acc[mt][nt] = __builtin_amdgcn_mfma_f32_16x16x32_bf16(
          af[mt], bf[nt], acc[mt][nt], 0, 0, 0);
}

// ---------------- CSR build ----------------
__global__ void hist_kernel(const int* __restrict__ eidx, int* __restrict__ counts,
                            int E) {
  int i = blockIdx.x * 256 + threadIdx.x;
  if (i < E) atomicAdd(&counts[eidx[E + i]], 1);
}

__global__ __launch_bounds__(1024) void scan_kernel(const int* __restrict__ counts,
                                                    int* __restrict__ row_ptr,
                                                    int* __restrict__ cursor, int Nn) {
  __shared__ int part[1024];
  const int t = threadIdx.x;
  const int chunk = (Nn + 1023) >> 10;
  const int lo = t * chunk;
  const int hi = min(lo + chunk, Nn);
  int s = 0;
  for (int i = lo; i < hi; ++i) s += counts[i];
  part[t] = s;
  __syncthreads();
  for (int off = 1; off < 1024; off <<= 1) {
    int add = (t >= off) ? part[t - off] : 0;
    __syncthreads();
    part[t] += add;
    __syncthreads();
  }
  int run = (t == 0) ? 0 : part[t - 1];
  for (int i = lo; i < hi; ++i) {
    row_ptr[i] = run;
    cursor[i] = run;
    run += counts[i];
  }
}

__global__ void build_kernel(const int* __restrict__ eidx, int* __restrict__ cursor,
                             int* __restrict__ perm, int* __restrict__ snds, int E) {
  int i = blockIdx.x * 256 + threadIdx.x;
  if (i < E) {
    int r = eidx[E + i];
    int pos = atomicAdd(&cursor[r], 1);
    perm[pos] = i;
    snds[pos] = eidx[i];
  }
}

// ---------------- per-receiver input sums (one wave per receiver) ----------------
__global__ __launch_bounds__(256) void aggsum_kernel(
    const float* __restrict__ nodes, const float* __restrict__ eattr,
    const int* __restrict__ row_ptr, const int* __restrict__ rend,
    const int* __restrict__ perm, const int* __restrict__ snds,
    float* __restrict__ S, int Nn) {
  const int wid = blockIdx.x * 4 + (threadIdx.x >> 6);
  if (wid >= Nn) return;
  const int lane = threadIdx.x & 63;
  int j = row_ptr[wid];
  const int end = rend[wid];
  float s0 = 0.f, s1 = 0.f, se = 0.f;
  for (; j < end; ++j) {
    int snd = snds[j];
    float2 v = ((const float2*)nodes)[(size_t)snd * 64 + lane];
    s0 += v.x;
    s1 += v.y;
    if (lane < 32) se += eattr[(size_t)perm[j] * 32 + lane];
  }
  ((float2*)S)[(size_t)wid * 80 + lane] = make_float2(s0, s1);
  if (lane < 32) S[(size_t)wid * 160 + 128 + lane] = se;
}

// ---------------- combined weight: Wcat = [W1a | W1b @ Wm] ----------------
// W1 [128][256], Wm [128][160], Wcat [128][288]
__global__ void wcat_kernel(const float* __restrict__ W1, const float* __restrict__ Wm,
                            float* __restrict__ Wcat) {
  const int jrow = blockIdx.x;
  for (int t = threadIdx.x; t < 288; t += 256) {
    if (t < 128) {
      Wcat[(size_t)jrow * 288 + t] = W1[(size_t)jrow * 256 + t];
    } else {
      int u = t - 128;
      float s = 0.f;
#pragma unroll 8
      for (int k = 0; k < 128; ++k)
        s += W1[(size_t)jrow * 256 + 128 + k] * Wm[(size_t)k * 160 + u];
      Wcat[(size_t)jrow * 288 + 128 + u] = s;
    }
  }
}

// ---------------- node GEMM + bias/relu/residual + LayerNorm ----------------
// MODE 0: A = [A0(nodes, pitch 128) | A1(S, pitch 160)] (K=288), +bias, relu, LN
// MODE 1: A = A0 (K=128), +bias, relu, LN
// MODE 2: A = A0 (K=128), no bias, + residual A1[row], LN
template <int KT, int MODE>
__global__ __launch_bounds__(THREADS, 4) void node_kernel(
    const float* __restrict__ A0, const float* __restrict__ A1,
    const float* __restrict__ W, const float* __restrict__ bias,
    const float* __restrict__ g, const float* __restrict__ bln,
    float* __restrict__ out, int Nn) {
  __shared__ NodeSmem sm;
  const int tid = threadIdx.x;
  const int row0 = blockIdx.x * BM;

  f32x4 acc[2][4];
#pragma unroll
  for (int mt = 0; mt < 2; ++mt)
#pragma unroll
    for (int nt = 0; nt < 4; ++nt) acc[mt][nt] = (f32x4)0.f;

  for (int kc = 0; kc < KT; kc += BK) {
#pragma unroll
    for (int c = 0; c < 2; ++c) {
      int f = tid + THREADS * c;
      int r = f >> 3, u = f & 7;
      int k = kc + 4 * u;
      int row = row0 + r;
      if (row >= Nn) row = Nn - 1;
      float4 v;
      if (MODE == 0) {
        if (k < 128)
          v = *(const float4*)&A0[(size_t)row * 128 + k];
        else
          v = *(const float4*)&A1[(size_t)row * 160 + (k - 128)];
      } else {
        v = *(const float4*)&A0[(size_t)row * 128 + k];
      }
      store_bf4(&sm.g.As[r][4 * u], v);
    }
    load_B<KT>(sm.g, W, kc, tid);
    __syncthreads();
    gemm_chunk(sm.g, tid, acc);
    __syncthreads();
  }

  const int lane = tid & 63;
  const int quad = lane >> 4;
  const int lm = lane & 15;
  const int wid = tid >> 6;
  const int wy = wid >> 1, wx = wid & 1;

  float bval[4] = {0.f, 0.f, 0.f, 0.f};
  if (MODE < 2) {
#pragma unroll
    for (int nt = 0; nt < 4; ++nt) bval[nt] = bias[64 * wx + 16 * nt + lm];
  }
#pragma unroll
  for (int mt = 0; mt < 2; ++mt) {
#pragma unroll
    for (int i = 0; i < 4; ++i) {
      int r = 32 * wy + 16 * mt + quad * 4 + i;
      int row = row0 + r;
      if (row >= Nn) row = Nn - 1;
#pragma unroll
      for (int nt = 0; nt < 4; ++nt) {
        int col = 64 * wx + 16 * nt + lm;
        float v = acc[mt][nt][i];
        if (MODE < 2) v = fmaxf(v + bval[nt], 0.f);
        if (MODE == 2) v += A1[(size_t)row * 128 + col];
        sm.e.Cs[r][col] = v;
      }
    }
  }
  __syncthreads();

  {
    int q = tid & 3, r = tid >> 2;
    float s = 0.f, s2 = 0.f;
#pragma unroll 8
    for (int j = q * 32; j < q * 32 + 32; ++j) {
      float x = sm.e.Cs[r][j];
      s += x;
      s2 += x * x;
    }
    sm.e.psum[r][q] = s;
    sm.e.psq[r][q] = s2;
  }
  __syncthreads();
  if (tid < BM) {
    float S_ = 0.f, S2 = 0.f;
#pragma unroll
    for (int q = 0; q < 4; ++q) {
      S_ += sm.e.psum[tid][q];
      S2 += sm.e.psq[tid][q];
    }
    float m = S_ * (1.f / 128.f);
    float var = S2 * (1.f / 128.f) - m * m;
    sm.e.mu[tid] = m;
    sm.e.rs[tid] = rsqrtf(var + 1e-5f);
  }
  __syncthreads();

#pragma unroll 4
  for (int s = 0; s < 32; ++s) {
    int flat = tid + THREADS * s;
    int r = flat >> 7, j = flat & 127;
    int row = row0 + r;
    if (row < Nn) {
      float x = sm.e.Cs[r][j];
      out[(size_t)row * 128 + j] =
          (x - sm.e.mu[r]) * sm.e.rs[r] * g[j] + bln[j];
    }
  }
}

extern "C" void kernel_launch(void* const* d_in, const int* in_sizes, int n_in,
                              void* d_out, int out_size, void* d_ws, size_t ws_size,
                              hipStream_t stream) {
  const float* nodes = (const float*)d_in[0];
  const int* eidx    = (const int*)d_in[1];
  const float* eattr = (const float*)d_in[2];
  const float* Wm    = (const float*)d_in[3];
  const float* Wn    = (const float*)d_in[4];
  const float* W1    = (const float*)d_in[5];
  const float* b1    = (const float*)d_in[6];
  const float* g1    = (const float*)d_in[7];
  const float* bl1   = (const float*)d_in[8];
  const float* W2    = (const float*)d_in[9];
  const float* b2    = (const float*)d_in[10];
  const float* g2    = (const float*)d_in[11];
  const float* bl2   = (const float*)d_in[12];
  const float* gf    = (const float*)d_in[13];
  const float* blf   = (const float*)d_in[14];
  float* out = (float*)d_out;

  const int Nn = in_sizes[0] / 128;   // 100000
  const int E  = in_sizes[2] / 32;    // 800000

  // workspace layout (16B-aligned sections)
  int* counts  = (int*)d_ws;                    // [Nn]
  int* row_ptr = counts + Nn;                   // [Nn]
  int* cursor  = row_ptr + Nn;                  // [Nn]  (== segment ends after build)
  int* perm    = cursor + Nn;                   // [E]
  int* snds    = perm + E;                      // [E]
  float* Wcat  = (float*)(snds + E);            // [128*288]
  float* S     = Wcat + 128 * 288;              // [Nn*160]; node_out aliases this later
  float* h     = S + (size_t)Nn * 160;          // [Nn*128]
  float* node_out = S;                          // reuse: S dead after node1

  hipMemsetAsync(counts, 0, (size_t)Nn * sizeof(int), stream);

  const int egrid = (E + 255) / 256;
  const int ngrid = (Nn + BM - 1) / BM;

  hist_kernel<<<egrid, 256, 0, stream>>>(eidx, counts, E);
  scan_kernel<<<1, 1024, 0, stream>>>(counts, row_ptr, cursor, Nn);
  build_kernel<<<egrid, 256, 0, stream>>>(eidx, cursor, perm, snds, E);
  aggsum_kernel<<<(Nn + 3) / 4, 256, 0, stream>>>(nodes, eattr, row_ptr, cursor,
                                                  perm, snds, S, Nn);
  wcat_kernel<<<128, 256, 0, stream>>>(W1, Wm, Wcat);

  node_kernel<288, 0><<<ngrid, THREADS, 0, stream>>>(nodes, S, Wcat, b1, g1, bl1, h, Nn);
  node_kernel<128, 1><<<ngrid, THREADS, 0, stream>>>(h, nullptr, W2, b2, g2, bl2, node_out, Nn);
  node_kernel<128, 2><<<ngrid, THREADS, 0, stream>>>(nodes, node_out, Wn, nullptr, gf, blf, out, Nn);
}

// Round 4
// 580.810 us; speedup vs baseline: 1.4122x; 1.4122x over previous
//
#include <hip/hip_runtime.h>
#include <math.h>

// GNN message-passing layer — linearity restructure + all-bf16 GEMM operands.
//   agg[r] = (sum x_snd) @ Wm_x^T + (sum e_attr) @ Wm_e^T   (message fn is linear)
// Pipeline:
//   memset counts
//   prep:  Wcat=[W1a | W1b@Wm]->bf16, W2/Wn->bf16, nodes->bf16, hist(receivers)
//   scan1/scan2/scan3: parallel exclusive scan -> row_ptr, cursor
//   build: CSR perm/snds (int atomics on cursor)
//   aggsum: S[r] = [sum nodes_bf[snd] | sum eattr]  -> bf16 (one wave per receiver)
//   node<288,0>: h(bf16)   = LN(relu([nodes_bf|S] @ Wcat^T + b1))
//   node<128,1>: node_out  = LN(relu(h @ W2^T + b2))          (fp32)
//   node<128,2>: out       = LN(nodes_bf @ Wn^T + node_out)
// GEMMs: bf16 LDS tiles (pure 16B copy staging) -> v_mfma_f32_16x16x32_bf16.
// Block tile M=64 x N=128, BK=32, 4 waves 2x2, each wave 32x64 (2x4 16x16 tiles).

#define THREADS 256
#define BM 64
#define BK 32
#define APB 40   // LDS row pitch in bf16 (80B rows: 20-bank stride -> <=2-way alias, free)
#define BP 132   // Cs row pitch (floats)

typedef __attribute__((ext_vector_type(8))) short bf16x8;
typedef __attribute__((ext_vector_type(4))) float f32x4;

struct GemmSmem {
  unsigned short As[BM][APB];
  unsigned short Bs[128][APB];
};
struct EpiSmem {
  float Cs[BM][BP];
  float psum[BM][4];
  float psq[BM][4];
  float mu[BM];
  float rs[BM];
};
union NodeSmem { GemmSmem g; EpiSmem e; };

union BF8 { bf16x8 v; ushort4 q[2]; };

__device__ __forceinline__ unsigned short f2bf(float x) {
  union { float f; unsigned u; } c; c.f = x;
  unsigned u = c.u;
  u += 0x7fffu + ((u >> 16) & 1u);   // RNE
  return (unsigned short)(u >> 16);
}
__device__ __forceinline__ float bf2f(unsigned h) {
  union { unsigned u; float f; } c; c.u = h << 16; return c.f;
}
__device__ __forceinline__ ushort4 cvt4(float4 v) {
  ushort4 p; p.x = f2bf(v.x); p.y = f2bf(v.y); p.z = f2bf(v.z); p.w = f2bf(v.w);
  return p;
}

// ---------------- prep: weight fold/convert + nodes->bf16 + receiver histogram ----
__global__ __launch_bounds__(256) void prep_kernel(
    const float* __restrict__ W1, const float* __restrict__ Wm,
    const float* __restrict__ W2, const float* __restrict__ Wn,
    const float* __restrict__ nodes, const int* __restrict__ eidx,
    unsigned short* __restrict__ Wcat, unsigned short* __restrict__ W2b,
    unsigned short* __restrict__ Wnb, unsigned short* __restrict__ nodes_bf,
    int* __restrict__ counts, int Nn, int E, int nconv) {
  const int b = blockIdx.x, tid = threadIdx.x;
  if (b < 128) {
    // Wcat row b: [W1[b,:128] | W1[b,128:] @ Wm] -> bf16
    for (int t = tid; t < 288; t += 256) {
      float v;
      if (t < 128) {
        v = W1[(size_t)b * 256 + t];
      } else {
        int u = t - 128;
        float s = 0.f;
#pragma unroll 8
        for (int k = 0; k < 128; ++k)
          s += W1[(size_t)b * 256 + 128 + k] * Wm[(size_t)k * 160 + u];
        v = s;
      }
      Wcat[(size_t)b * 288 + t] = f2bf(v);
    }
  } else if (b < 144) {
    int idx = (b - 128) * 1024 + tid * 4;
    *(ushort4*)&W2b[idx] = cvt4(*(const float4*)&W2[idx]);
  } else if (b < 160) {
    int idx = (b - 144) * 1024 + tid * 4;
    *(ushort4*)&Wnb[idx] = cvt4(*(const float4*)&Wn[idx]);
  } else if (b < 160 + nconv) {
    int idx = ((b - 160) * 256 + tid) * 4;
    if (idx < Nn * 128)
      *(ushort4*)&nodes_bf[idx] = cvt4(*(const float4*)&nodes[idx]);
  } else {
    int i = (b - 160 - nconv) * 256 + tid;
    if (i < E) atomicAdd(&counts[eidx[E + i]], 1);
  }
}

// ---------------- parallel exclusive scan over counts ----------------
__global__ __launch_bounds__(256) void scan1_kernel(const int* __restrict__ counts,
                                                    int* __restrict__ bsum, int Nn) {
  __shared__ int red[256];
  const int tid = threadIdx.x;
  int base = blockIdx.x * 2048 + tid * 8;
  int s = 0;
#pragma unroll
  for (int i = 0; i < 8; ++i) {
    int idx = base + i;
    if (idx < Nn) s += counts[idx];
  }
  red[tid] = s;
  __syncthreads();
#pragma unroll
  for (int off = 128; off; off >>= 1) {
    if (tid < off) red[tid] += red[tid + off];
    __syncthreads();
  }
  if (tid == 0) bsum[blockIdx.x] = red[0];
}

__global__ __launch_bounds__(256) void scan2_kernel(const int* __restrict__ bsum,
                                                    int* __restrict__ boff, int NB) {
  __shared__ int arr[256];
  const int tid = threadIdx.x;
  int v = (tid < NB) ? bsum[tid] : 0;
  arr[tid] = v;
  __syncthreads();
  for (int off = 1; off < 256; off <<= 1) {
    int t2 = (tid >= off) ? arr[tid - off] : 0;
    __syncthreads();
    arr[tid] += t2;
    __syncthreads();
  }
  if (tid < NB) boff[tid] = arr[tid] - v;   // exclusive
}

__global__ __launch_bounds__(256) void scan3_kernel(const int* __restrict__ counts,
                                                    const int* __restrict__ boff,
                                                    int* __restrict__ row_ptr,
                                                    int* __restrict__ cursor, int Nn) {
  __shared__ int arr[256];
  const int tid = threadIdx.x;
  int base = blockIdx.x * 2048 + tid * 8;
  int c[8];
  int s = 0;
#pragma unroll
  for (int i = 0; i < 8; ++i) {
    int idx = base + i;
    c[i] = (idx < Nn) ? counts[idx] : 0;
    s += c[i];
  }
  arr[tid] = s;
  __syncthreads();
  for (int off = 1; off < 256; off <<= 1) {
    int t2 = (tid >= off) ? arr[tid - off] : 0;
    __syncthreads();
    arr[tid] += t2;
    __syncthreads();
  }
  int run = arr[tid] - s + boff[blockIdx.x];
#pragma unroll
  for (int i = 0; i < 8; ++i) {
    int idx = base + i;
    if (idx < Nn) {
      row_ptr[idx] = run;
      cursor[idx] = run;
    }
    run += c[i];
  }
}

__global__ __launch_bounds__(256) void build_kernel(const int* __restrict__ eidx,
                                                    int* __restrict__ cursor,
                                                    int* __restrict__ perm,
                                                    int* __restrict__ snds, int E) {
  int i = blockIdx.x * 256 + threadIdx.x;
  if (i < E) {
    int r = eidx[E + i];
    int pos = atomicAdd(&cursor[r], 1);
    perm[pos] = i;
    snds[pos] = eidx[i];
  }
}

// ---------------- per-receiver input sums (one wave per receiver), bf16 out ------
__global__ __launch_bounds__(256) void aggsum_kernel(
    const unsigned short* __restrict__ nodes_bf, const float* __restrict__ eattr,
    const int* __restrict__ row_ptr, const int* __restrict__ rend,
    const int* __restrict__ perm, const int* __restrict__ snds,
    unsigned short* __restrict__ S, int Nn) {
  const int wid = blockIdx.x * 4 + (threadIdx.x >> 6);
  if (wid >= Nn) return;
  const int lane = threadIdx.x & 63;
  int j = row_ptr[wid];
  const int end = rend[wid];
  float s0 = 0.f, s1 = 0.f, se = 0.f;
  for (; j < end; ++j) {
    int snd = snds[j];
    unsigned v = ((const unsigned*)nodes_bf)[(size_t)snd * 64 + lane];
    s0 += bf2f(v & 0xffffu);
    s1 += bf2f(v >> 16);
    if (lane < 32) se += eattr[(size_t)perm[j] * 32 + lane];
  }
  unsigned pack = (unsigned)f2bf(s0) | ((unsigned)f2bf(s1) << 16);
  ((unsigned*)S)[(size_t)wid * 80 + lane] = pack;
  if (lane < 32) S[(size_t)wid * 160 + 128 + lane] = f2bf(se);
}

// ---------------- node GEMM + bias/relu/residual + LayerNorm ----------------
// MODE 0: A=[nodes_bf | S_bf] K=288, +bias, relu, LN, OUT bf16
// MODE 1: A=A0 bf16 K=128, +bias, relu, LN, OUT fp32
// MODE 2: A=A0 bf16 K=128, + residual A1(fp32), LN, OUT fp32
__device__ __forceinline__ void gemm_chunk(const GemmSmem& sm, int tid,
                                           f32x4 acc[2][4]) {
  const int lane = tid & 63;
  const int quad = lane >> 4;
  const int lm = lane & 15;
  const int wid = tid >> 6;
  const int wy = wid >> 1, wx = wid & 1;

  bf16x8 af[2], bf[4];
#pragma unroll
  for (int mt = 0; mt < 2; ++mt)
    af[mt] = *(const bf16x8*)&sm.As[32 * wy + 16 * mt + lm][quad * 8];
#pragma unroll
  for (int nt = 0; nt < 4; ++nt)
    bf[nt] = *(const bf16x8*)&sm.Bs[64 * wx + 16 * nt + lm][quad * 8];
#pragma unroll
  for (int mt = 0; mt < 2; ++mt)
#pragma unroll
    for (int nt = 0; nt < 4; ++nt)
      acc[mt][nt] = __builtin_amdgcn_mfma_f32_16x16x32_bf16(
          af[mt], bf[nt], acc[mt][nt], 0, 0, 0);
}

template <int KT, int MODE>
__global__ __launch_bounds__(THREADS, 4) void node_kernel(
    const unsigned short* __restrict__ A0, const void* __restrict__ A1v,
    const unsigned short* __restrict__ Wb, const float* __restrict__ bias,
    const float* __restrict__ g, const float* __restrict__ bln,
    void* __restrict__ outv, int Nn) {
  __shared__ NodeSmem sm;
  const int tid = threadIdx.x;
  const int row0 = blockIdx.x * BM;
  const unsigned short* A1b = (const unsigned short*)A1v;
  const float* A1f = (const float*)A1v;

  f32x4 acc[2][4];
#pragma unroll
  for (int mt = 0; mt < 2; ++mt)
#pragma unroll
    for (int nt = 0; nt < 4; ++nt) acc[mt][nt] = (f32x4)0.f;

  for (int kc = 0; kc < KT; kc += BK) {
    // A: 64 rows x 32 k — one bf16x8 per thread
    {
      int r = tid >> 2, u = tid & 3;
      int k = kc + 8 * u;
      int row = row0 + r;
      if (row >= Nn) row = Nn - 1;
      BF8 t;
      if (MODE == 0 && kc >= 128)
        t.v = *(const bf16x8*)&A1b[(size_t)row * 160 + (k - 128)];
      else
        t.v = *(const bf16x8*)&A0[(size_t)row * 128 + k];
      *(ushort4*)&sm.g.As[r][8 * u] = t.q[0];
      *(ushort4*)&sm.g.As[r][8 * u + 4] = t.q[1];
    }
    // B: 128 n x 32 k — two bf16x8 per thread
#pragma unroll
    for (int c = 0; c < 2; ++c) {
      int f = tid + 256 * c;
      int n = f >> 2, u = f & 3;
      BF8 t;
      t.v = *(const bf16x8*)&Wb[(size_t)n * KT + kc + 8 * u];
      *(ushort4*)&sm.g.Bs[n][8 * u] = t.q[0];
      *(ushort4*)&sm.g.Bs[n][8 * u + 4] = t.q[1];
    }
    __syncthreads();
    gemm_chunk(sm.g, tid, acc);
    __syncthreads();
  }

  const int lane = tid & 63;
  const int quad = lane >> 4;
  const int lm = lane & 15;
  const int wid = tid >> 6;
  const int wy = wid >> 1, wx = wid & 1;

  float bval[4] = {0.f, 0.f, 0.f, 0.f};
  if (MODE < 2) {
#pragma unroll
    for (int nt = 0; nt < 4; ++nt) bval[nt] = bias[64 * wx + 16 * nt + lm];
  }
#pragma unroll
  for (int mt = 0; mt < 2; ++mt) {
#pragma unroll
    for (int i = 0; i < 4; ++i) {
      int r = 32 * wy + 16 * mt + quad * 4 + i;
      int row = row0 + r;
      if (row >= Nn) row = Nn - 1;
#pragma unroll
      for (int nt = 0; nt < 4; ++nt) {
        int col = 64 * wx + 16 * nt + lm;
        float v = acc[mt][nt][i];
        if (MODE < 2) v = fmaxf(v + bval[nt], 0.f);
        if (MODE == 2) v += A1f[(size_t)row * 128 + col];
        sm.e.Cs[r][col] = v;
      }
    }
  }
  __syncthreads();

  {
    int q = tid & 3, r = tid >> 2;
    float s = 0.f, s2 = 0.f;
#pragma unroll 8
    for (int j = q * 32; j < q * 32 + 32; ++j) {
      float x = sm.e.Cs[r][j];
      s += x;
      s2 += x * x;
    }
    sm.e.psum[r][q] = s;
    sm.e.psq[r][q] = s2;
  }
  __syncthreads();
  if (tid < BM) {
    float S_ = 0.f, S2 = 0.f;
#pragma unroll
    for (int q = 0; q < 4; ++q) {
      S_ += sm.e.psum[tid][q];
      S2 += sm.e.psq[tid][q];
    }
    float m = S_ * (1.f / 128.f);
    float var = S2 * (1.f / 128.f) - m * m;
    sm.e.mu[tid] = m;
    sm.e.rs[tid] = rsqrtf(var + 1e-5f);
  }
  __syncthreads();

#pragma unroll 4
  for (int s = 0; s < 32; ++s) {
    int flat = tid + THREADS * s;
    int r = flat >> 7, j = flat & 127;
    int row = row0 + r;
    if (row < Nn) {
      float x = sm.e.Cs[r][j];
      float y = (x - sm.e.mu[r]) * sm.e.rs[r] * g[j] + bln[j];
      if (MODE == 0)
        ((unsigned short*)outv)[(size_t)row * 128 + j] = f2bf(y);
      else
        ((float*)outv)[(size_t)row * 128 + j] = y;
    }
  }
}

extern "C" void kernel_launch(void* const* d_in, const int* in_sizes, int n_in,
                              void* d_out, int out_size, void* d_ws, size_t ws_size,
                              hipStream_t stream) {
  const float* nodes = (const float*)d_in[0];
  const int* eidx    = (const int*)d_in[1];
  const float* eattr = (const float*)d_in[2];
  const float* Wm    = (const float*)d_in[3];
  const float* Wn    = (const float*)d_in[4];
  const float* W1    = (const float*)d_in[5];
  const float* b1    = (const float*)d_in[6];
  const float* g1    = (const float*)d_in[7];
  const float* bl1   = (const float*)d_in[8];
  const float* W2    = (const float*)d_in[9];
  const float* b2    = (const float*)d_in[10];
  const float* g2    = (const float*)d_in[11];
  const float* bl2   = (const float*)d_in[12];
  const float* gf    = (const float*)d_in[13];
  const float* blf   = (const float*)d_in[14];
  float* out = (float*)d_out;

  const int Nn = in_sizes[0] / 128;   // 100000
  const int E  = in_sizes[2] / 32;    // 800000

  // workspace layout (all 16B-aligned)
  int* counts  = (int*)d_ws;                       // [Nn]
  int* row_ptr = counts + Nn;                      // [Nn]
  int* cursor  = row_ptr + Nn;                     // [Nn] (ends after build)
  int* bsum    = cursor + Nn;                      // [256]
  int* boff    = bsum + 256;                       // [256]
  int* perm    = boff + 256;                       // [E]
  int* snds    = perm + E;                         // [E]
  unsigned short* Wcat     = (unsigned short*)(snds + E);       // [128*288]
  unsigned short* W2b      = Wcat + 128 * 288;                  // [128*128]
  unsigned short* Wnb      = W2b + 128 * 128;                   // [128*128]
  unsigned short* nodes_bf = Wnb + 128 * 128;                   // [Nn*128]
  unsigned short* h_bf     = nodes_bf + (size_t)Nn * 128;       // [Nn*128]
  unsigned short* S_bf     = h_bf + (size_t)Nn * 128;           // [Nn*160]
  float* node_out = (float*)S_bf;  // [Nn*128] fp32 — overlays S (dead) + tail

  hipMemsetAsync(counts, 0, (size_t)Nn * sizeof(int), stream);

  const int nconv = (Nn * 32 + 255) / 256;   // nodes float4 chunks
  const int nhist = (E + 255) / 256;
  const int NB = (Nn + 2047) / 2048;
  const int ngrid = (Nn + BM - 1) / BM;

  prep_kernel<<<160 + nconv + nhist, 256, 0, stream>>>(
      W1, Wm, W2, Wn, nodes, eidx, Wcat, W2b, Wnb, nodes_bf, counts, Nn, E, nconv);
  scan1_kernel<<<NB, 256, 0, stream>>>(counts, bsum, Nn);
  scan2_kernel<<<1, 256, 0, stream>>>(bsum, boff, NB);
  scan3_kernel<<<NB, 256, 0, stream>>>(counts, boff, row_ptr, cursor, Nn);
  build_kernel<<<nhist, 256, 0, stream>>>(eidx, cursor, perm, snds, E);
  aggsum_kernel<<<(Nn + 3) / 4, 256, 0, stream>>>(nodes_bf, eattr, row_ptr, cursor,
                                                  perm, snds, S_bf, Nn);

  node_kernel<288, 0><<<ngrid, THREADS, 0, stream>>>(nodes_bf, S_bf, Wcat, b1, g1,
                                                     bl1, h_bf, Nn);
  node_kernel<128, 1><<<ngrid, THREADS, 0, stream>>>(h_bf, nullptr, W2b, b2, g2,
                                                     bl2, node_out, Nn);
  node_kernel<128, 2><<<ngrid, THREADS, 0, stream>>>(nodes_bf, node_out, Wnb,
                                                     nullptr, gf, blf, out, Nn);
}

// Round 5
// 448.904 us; speedup vs baseline: 1.8271x; 1.2938x over previous
//
#include <hip/hip_runtime.h>
#include <math.h>

// GNN message-passing layer — linearity restructure + bf16 MFMA + ILP'd gather.
//   agg[r] = (sum x_snd) @ Wm_x^T + (sum e_attr) @ Wm_e^T   (message fn is linear)
// Pipeline:
//   memset counts
//   prep:  Wcat=[W1a | W1b@Wm]->bf16, W2/Wn->bf16, nodes->bf16, hist(receivers)
//   scan1/2/3: parallel exclusive scan -> row_ptr, cursor
//   build: CSR perm/snds
//   aggsum: S[r] = [sum nodes_bf[snd] | sum eattr] -> bf16
//           (wave/receiver, 64-index shfl-prefetch, 4-edge unroll -> 6 loads in flight)
//   node0:  h(bf16) = LN(relu([nodes_bf|S] @ Wcat^T + b1))     K=288
//   node12: out     = LN(nodes_bf @ Wn^T + LN(relu(h @ W2^T + b2)))   (fused)
// GEMMs: bf16 LDS tiles (16B copy staging) -> v_mfma_f32_16x16x32_bf16.
// Block tile M=64 x N=128, BK=32, 4 waves 2x2, each wave 32x64 (2x4 16x16 tiles).

#define THREADS 256
#define BM 64
#define BK 32
#define APB 40   // LDS row pitch in bf16 (80B rows -> <=2-way bank alias, free)
#define BP 132   // Cs row pitch (floats)

typedef __attribute__((ext_vector_type(8))) short bf16x8;
typedef __attribute__((ext_vector_type(4))) float f32x4;

struct GemmSmem {
  unsigned short As[BM][APB];
  unsigned short Bs[128][APB];
};
struct EpiSmem {
  float Cs[BM][BP];
  float psum[BM][4];
  float psq[BM][4];
  float mu[BM];
  float rs[BM];
};
union NodeSmem { GemmSmem g; EpiSmem e; };

union BF8 { bf16x8 v; ushort4 q[2]; };

__device__ __forceinline__ unsigned short f2bf(float x) {
  union { float f; unsigned u; } c; c.f = x;
  unsigned u = c.u;
  u += 0x7fffu + ((u >> 16) & 1u);   // RNE
  return (unsigned short)(u >> 16);
}
__device__ __forceinline__ float bf2f(unsigned h) {
  union { unsigned u; float f; } c; c.u = h << 16; return c.f;
}
__device__ __forceinline__ ushort4 cvt4(float4 v) {
  ushort4 p; p.x = f2bf(v.x); p.y = f2bf(v.y); p.z = f2bf(v.z); p.w = f2bf(v.w);
  return p;
}

// ---------------- prep: weight fold/convert + nodes->bf16 + receiver histogram ----
__global__ __launch_bounds__(256) void prep_kernel(
    const float* __restrict__ W1, const float* __restrict__ Wm,
    const float* __restrict__ W2, const float* __restrict__ Wn,
    const float* __restrict__ nodes, const int* __restrict__ eidx,
    unsigned short* __restrict__ Wcat, unsigned short* __restrict__ W2b,
    unsigned short* __restrict__ Wnb, unsigned short* __restrict__ nodes_bf,
    int* __restrict__ counts, int Nn, int E, int nconv) {
  const int b = blockIdx.x, tid = threadIdx.x;
  if (b < 128) {
    for (int t = tid; t < 288; t += 256) {
      float v;
      if (t < 128) {
        v = W1[(size_t)b * 256 + t];
      } else {
        int u = t - 128;
        float s = 0.f;
#pragma unroll 8
        for (int k = 0; k < 128; ++k)
          s += W1[(size_t)b * 256 + 128 + k] * Wm[(size_t)k * 160 + u];
        v = s;
      }
      Wcat[(size_t)b * 288 + t] = f2bf(v);
    }
  } else if (b < 144) {
    int idx = (b - 128) * 1024 + tid * 4;
    *(ushort4*)&W2b[idx] = cvt4(*(const float4*)&W2[idx]);
  } else if (b < 160) {
    int idx = (b - 144) * 1024 + tid * 4;
    *(ushort4*)&Wnb[idx] = cvt4(*(const float4*)&Wn[idx]);
  } else if (b < 160 + nconv) {
    int idx = ((b - 160) * 256 + tid) * 4;
    if (idx < Nn * 128)
      *(ushort4*)&nodes_bf[idx] = cvt4(*(const float4*)&nodes[idx]);
  } else {
    int i = (b - 160 - nconv) * 256 + tid;
    if (i < E) atomicAdd(&counts[eidx[E + i]], 1);
  }
}

// ---------------- parallel exclusive scan over counts ----------------
__global__ __launch_bounds__(256) void scan1_kernel(const int* __restrict__ counts,
                                                    int* __restrict__ bsum, int Nn) {
  __shared__ int red[256];
  const int tid = threadIdx.x;
  int base = blockIdx.x * 2048 + tid * 8;
  int s = 0;
#pragma unroll
  for (int i = 0; i < 8; ++i) {
    int idx = base + i;
    if (idx < Nn) s += counts[idx];
  }
  red[tid] = s;
  __syncthreads();
#pragma unroll
  for (int off = 128; off; off >>= 1) {
    if (tid < off) red[tid] += red[tid + off];
    __syncthreads();
  }
  if (tid == 0) bsum[blockIdx.x] = red[0];
}

__global__ __launch_bounds__(256) void scan2_kernel(const int* __restrict__ bsum,
                                                    int* __restrict__ boff, int NB) {
  __shared__ int arr[256];
  const int tid = threadIdx.x;
  int v = (tid < NB) ? bsum[tid] : 0;
  arr[tid] = v;
  __syncthreads();
  for (int off = 1; off < 256; off <<= 1) {
    int t2 = (tid >= off) ? arr[tid - off] : 0;
    __syncthreads();
    arr[tid] += t2;
    __syncthreads();
  }
  if (tid < NB) boff[tid] = arr[tid] - v;   // exclusive
}

__global__ __launch_bounds__(256) void scan3_kernel(const int* __restrict__ counts,
                                                    const int* __restrict__ boff,
                                                    int* __restrict__ row_ptr,
                                                    int* __restrict__ cursor, int Nn) {
  __shared__ int arr[256];
  const int tid = threadIdx.x;
  int base = blockIdx.x * 2048 + tid * 8;
  int c[8];
  int s = 0;
#pragma unroll
  for (int i = 0; i < 8; ++i) {
    int idx = base + i;
    c[i] = (idx < Nn) ? counts[idx] : 0;
    s += c[i];
  }
  arr[tid] = s;
  __syncthreads();
  for (int off = 1; off < 256; off <<= 1) {
    int t2 = (tid >= off) ? arr[tid - off] : 0;
    __syncthreads();
    arr[tid] += t2;
    __syncthreads();
  }
  int run = arr[tid] - s + boff[blockIdx.x];
#pragma unroll
  for (int i = 0; i < 8; ++i) {
    int idx = base + i;
    if (idx < Nn) {
      row_ptr[idx] = run;
      cursor[idx] = run;
    }
    run += c[i];
  }
}

__global__ __launch_bounds__(256) void build_kernel(const int* __restrict__ eidx,
                                                    int* __restrict__ cursor,
                                                    int* __restrict__ perm,
                                                    int* __restrict__ snds, int E) {
  int i = blockIdx.x * 256 + threadIdx.x;
  if (i < E) {
    int r = eidx[E + i];
    int pos = atomicAdd(&cursor[r], 1);
    perm[pos] = i;
    snds[pos] = eidx[i];
  }
}

// ------- per-receiver input sums: shfl-prefetched indices, 4-edge unroll --------
__global__ __launch_bounds__(256) void aggsum_kernel(
    const unsigned short* __restrict__ nodes_bf, const float* __restrict__ eattr,
    const int* __restrict__ row_ptr, const int* __restrict__ rend,
    const int* __restrict__ perm, const int* __restrict__ snds,
    unsigned short* __restrict__ S, int Nn) {
  const int wid = blockIdx.x * 4 + (threadIdx.x >> 6);
  if (wid >= Nn) return;
  const int lane = threadIdx.x & 63;
  const int start = row_ptr[wid];
  const int end = rend[wid];
  const int deg = end - start;
  const int dmax = deg < 64 ? deg : 64;

  // one coalesced load grabs up to 64 CSR entries for this receiver
  int sv = 0, pv = 0;
  if (lane < deg) {
    sv = snds[start + lane];
    pv = perm[start + lane];
  }

  const unsigned* nodes32 = (const unsigned*)nodes_bf;
  const int rsub = lane >> 5;   // half-wave: which of 2 eattr rows per load
  const int col = lane & 31;
  float s0 = 0.f, s1 = 0.f, seA = 0.f, seB = 0.f;

  int t = 0;
  for (; t + 4 <= dmax; t += 4) {
    int i0 = __shfl(sv, t + 0);
    int i1 = __shfl(sv, t + 1);
    int i2 = __shfl(sv, t + 2);
    int i3 = __shfl(sv, t + 3);
    int pA = __shfl(pv, t + rsub);
    int pB = __shfl(pv, t + 2 + rsub);
    unsigned a0 = nodes32[(size_t)i0 * 64 + lane];
    unsigned a1 = nodes32[(size_t)i1 * 64 + lane];
    unsigned a2 = nodes32[(size_t)i2 * 64 + lane];
    unsigned a3 = nodes32[(size_t)i3 * 64 + lane];
    float vA = eattr[(size_t)pA * 32 + col];
    float vB = eattr[(size_t)pB * 32 + col];
    s0 += bf2f(a0 & 0xffffu) + bf2f(a1 & 0xffffu) +
          bf2f(a2 & 0xffffu) + bf2f(a3 & 0xffffu);
    s1 += bf2f(a0 >> 16) + bf2f(a1 >> 16) + bf2f(a2 >> 16) + bf2f(a3 >> 16);
    seA += vA;
    seB += vB;
  }
  for (; t < dmax; ++t) {
    int i0 = __shfl(sv, t);
    int p = __shfl(pv, t);
    unsigned a0 = nodes32[(size_t)i0 * 64 + lane];
    s0 += bf2f(a0 & 0xffffu);
    s1 += bf2f(a0 >> 16);
    if (rsub == 0) seA += eattr[(size_t)p * 32 + col];
  }
  // overflow path (deg > 64) — rare, wave-uniform
  for (int j = start + 64; j < end; ++j) {
    int sI = snds[j];
    int p = perm[j];
    unsigned a = nodes32[(size_t)sI * 64 + lane];
    s0 += bf2f(a & 0xffffu);
    s1 += bf2f(a >> 16);
    if (rsub == 0) seA += eattr[(size_t)p * 32 + col];
  }

  // eattr: combine interleaved rows, then halves
  float se = seA + seB;
  se += __shfl_xor(se, 32);

  unsigned pack = (unsigned)f2bf(s0) | ((unsigned)f2bf(s1) << 16);
  ((unsigned*)S)[(size_t)wid * 80 + lane] = pack;

  float lo = __shfl(se, 2 * (lane & 15));
  float hi = __shfl(se, 2 * (lane & 15) + 1);
  if (lane < 16) {
    unsigned p2 = (unsigned)f2bf(lo) | ((unsigned)f2bf(hi) << 16);
    ((unsigned*)S)[(size_t)wid * 80 + 64 + lane] = p2;
  }
}

// ---------------- shared GEMM pieces ----------------
__device__ __forceinline__ void gemm_chunk(const GemmSmem& sm, int tid,
                                           f32x4 acc[2][4]) {
  const int lane = tid & 63;
  const int quad = lane >> 4;
  const int lm = lane & 15;
  const int wid = tid >> 6;
  const int wy = wid >> 1, wx = wid & 1;

  bf16x8 af[2], bf[4];
#pragma unroll
  for (int mt = 0; mt < 2; ++mt)
    af[mt] = *(const bf16x8*)&sm.As[32 * wy + 16 * mt + lm][quad * 8];
#pragma unroll
  for (int nt = 0; nt < 4; ++nt)
    bf[nt] = *(const bf16x8*)&sm.Bs[64 * wx + 16 * nt + lm][quad * 8];
#pragma unroll
  for (int mt = 0; mt < 2; ++mt)
#pragma unroll
    for (int nt = 0; nt < 4; ++nt)
      acc[mt][nt] = __builtin_amdgcn_mfma_f32_16x16x32_bf16(
          af[mt], bf[nt], acc[mt][nt], 0, 0, 0);
}

__device__ __forceinline__ void gemm_k128(const unsigned short* __restrict__ A,
                                          const unsigned short* __restrict__ W,
                                          int row0, int Nn, GemmSmem& g, int tid,
                                          f32x4 acc[2][4]) {
  for (int kc = 0; kc < 128; kc += BK) {
    {
      int r = tid >> 2, u = tid & 3;
      int row = row0 + r;
      if (row >= Nn) row = Nn - 1;
      BF8 t;
      t.v = *(const bf16x8*)&A[(size_t)row * 128 + kc + 8 * u];
      *(ushort4*)&g.As[r][8 * u] = t.q[0];
      *(ushort4*)&g.As[r][8 * u + 4] = t.q[1];
    }
#pragma unroll
    for (int c = 0; c < 2; ++c) {
      int f = tid + 256 * c;
      int n = f >> 2, u = f & 3;
      BF8 t;
      t.v = *(const bf16x8*)&W[(size_t)n * 128 + kc + 8 * u];
      *(ushort4*)&g.Bs[n][8 * u] = t.q[0];
      *(ushort4*)&g.Bs[n][8 * u + 4] = t.q[1];
    }
    __syncthreads();
    gemm_chunk(g, tid, acc);
    __syncthreads();
  }
}

__device__ __forceinline__ void ln_stats(EpiSmem& e, int tid) {
  {
    int q = tid & 3, r = tid >> 2;
    float s = 0.f, s2 = 0.f;
#pragma unroll 8
    for (int j = q * 32; j < q * 32 + 32; ++j) {
      float x = e.Cs[r][j];
      s += x;
      s2 += x * x;
    }
    e.psum[r][q] = s;
    e.psq[r][q] = s2;
  }
  __syncthreads();
  if (tid < BM) {
    float S_ = 0.f, S2 = 0.f;
#pragma unroll
    for (int q = 0; q < 4; ++q) {
      S_ += e.psum[tid][q];
      S2 += e.psq[tid][q];
    }
    float m = S_ * (1.f / 128.f);
    float var = S2 * (1.f / 128.f) - m * m;
    e.mu[tid] = m;
    e.rs[tid] = rsqrtf(var + 1e-5f);
  }
  __syncthreads();
}

// ---------------- node0: h = LN(relu([nodes_bf|S] @ Wcat^T + b1)), K=288 --------
__global__ __launch_bounds__(THREADS, 4) void node0_kernel(
    const unsigned short* __restrict__ A0, const unsigned short* __restrict__ A1,
    const unsigned short* __restrict__ Wb, const float* __restrict__ bias,
    const float* __restrict__ g, const float* __restrict__ bln,
    unsigned short* __restrict__ outb, int Nn) {
  __shared__ NodeSmem sm;
  const int tid = threadIdx.x;
  const int row0 = blockIdx.x * BM;

  f32x4 acc[2][4];
#pragma unroll
  for (int mt = 0; mt < 2; ++mt)
#pragma unroll
    for (int nt = 0; nt < 4; ++nt) acc[mt][nt] = (f32x4)0.f;

  for (int kc = 0; kc < 288; kc += BK) {
    {
      int r = tid >> 2, u = tid & 3;
      int k = kc + 8 * u;
      int row = row0 + r;
      if (row >= Nn) row = Nn - 1;
      BF8 t;
      if (kc >= 128)
        t.v = *(const bf16x8*)&A1[(size_t)row * 160 + (k - 128)];
      else
        t.v = *(const bf16x8*)&A0[(size_t)row * 128 + k];
      *(ushort4*)&sm.g.As[r][8 * u] = t.q[0];
      *(ushort4*)&sm.g.As[r][8 * u + 4] = t.q[1];
    }
#pragma unroll
    for (int c = 0; c < 2; ++c) {
      int f = tid + 256 * c;
      int n = f >> 2, u = f & 3;
      BF8 t;
      t.v = *(const bf16x8*)&Wb[(size_t)n * 288 + kc + 8 * u];
      *(ushort4*)&sm.g.Bs[n][8 * u] = t.q[0];
      *(ushort4*)&sm.g.Bs[n][8 * u + 4] = t.q[1];
    }
    __syncthreads();
    gemm_chunk(sm.g, tid, acc);
    __syncthreads();
  }

  const int lane = tid & 63;
  const int quad = lane >> 4;
  const int lm = lane & 15;
  const int wid = tid >> 6;
  const int wy = wid >> 1, wx = wid & 1;

  float bval[4];
#pragma unroll
  for (int nt = 0; nt < 4; ++nt) bval[nt] = bias[64 * wx + 16 * nt + lm];
#pragma unroll
  for (int mt = 0; mt < 2; ++mt)
#pragma unroll
    for (int i = 0; i < 4; ++i) {
      int r = 32 * wy + 16 * mt + quad * 4 + i;
#pragma unroll
      for (int nt = 0; nt < 4; ++nt) {
        int col = 64 * wx + 16 * nt + lm;
        sm.e.Cs[r][col] = fmaxf(acc[mt][nt][i] + bval[nt], 0.f);
      }
    }
  __syncthreads();
  ln_stats(sm.e, tid);

#pragma unroll 4
  for (int s = 0; s < 32; ++s) {
    int flat = tid + THREADS * s;
    int r = flat >> 7, j = flat & 127;
    int row = row0 + r;
    if (row < Nn) {
      float x = sm.e.Cs[r][j];
      outb[(size_t)row * 128 + j] =
          f2bf((x - sm.e.mu[r]) * sm.e.rs[r] * g[j] + bln[j]);
    }
  }
}

// ------- node12 (fused): out = LN(nodes@Wn^T + LN(relu(h@W2^T + b2))) ----------
__global__ __launch_bounds__(THREADS, 3) void node12_kernel(
    const unsigned short* __restrict__ h_bf,
    const unsigned short* __restrict__ nodes_bf,
    const unsigned short* __restrict__ W2b, const unsigned short* __restrict__ Wnb,
    const float* __restrict__ b2, const float* __restrict__ g2,
    const float* __restrict__ bl2, const float* __restrict__ gf,
    const float* __restrict__ blf, float* __restrict__ out, int Nn) {
  __shared__ GemmSmem g;
  __shared__ EpiSmem e;
  const int tid = threadIdx.x;
  const int row0 = blockIdx.x * BM;
  const int lane = tid & 63;
  const int quad = lane >> 4;
  const int lm = lane & 15;
  const int wid = tid >> 6;
  const int wy = wid >> 1, wx = wid & 1;

  f32x4 acc[2][4];
#pragma unroll
  for (int mt = 0; mt < 2; ++mt)
#pragma unroll
    for (int nt = 0; nt < 4; ++nt) acc[mt][nt] = (f32x4)0.f;

  // ---- phase A: h @ W2^T, relu+b2, LN2 -> Cs (node_out tile) ----
  gemm_k128(h_bf, W2b, row0, Nn, g, tid, acc);

  float bval[4];
#pragma unroll
  for (int nt = 0; nt < 4; ++nt) bval[nt] = b2[64 * wx + 16 * nt + lm];
#pragma unroll
  for (int mt = 0; mt < 2; ++mt)
#pragma unroll
    for (int i = 0; i < 4; ++i) {
      int r = 32 * wy + 16 * mt + quad * 4 + i;
#pragma unroll
      for (int nt = 0; nt < 4; ++nt) {
        int col = 64 * wx + 16 * nt + lm;
        e.Cs[r][col] = fmaxf(acc[mt][nt][i] + bval[nt], 0.f);
      }
    }
  __syncthreads();
  ln_stats(e, tid);

  // rewrite Cs in normalized form (= node_out)
#pragma unroll 4
  for (int s = 0; s < 32; ++s) {
    int flat = tid + THREADS * s;
    int r = flat >> 7, j = flat & 127;
    float x = e.Cs[r][j];
    e.Cs[r][j] = (x - e.mu[r]) * e.rs[r] * g2[j] + bl2[j];
  }
  __syncthreads();

  // ---- phase B: nodes @ Wn^T + node_out, final LN ----
#pragma unroll
  for (int mt = 0; mt < 2; ++mt)
#pragma unroll
    for (int nt = 0; nt < 4; ++nt) acc[mt][nt] = (f32x4)0.f;

  gemm_k128(nodes_bf, Wnb, row0, Nn, g, tid, acc);

#pragma unroll
  for (int mt = 0; mt < 2; ++mt)
#pragma unroll
    for (int i = 0; i < 4; ++i) {
      int r = 32 * wy + 16 * mt + quad * 4 + i;
#pragma unroll
      for (int nt = 0; nt < 4; ++nt) {
        int col = 64 * wx + 16 * nt + lm;
        e.Cs[r][col] = acc[mt][nt][i] + e.Cs[r][col];
      }
    }
  __syncthreads();
  ln_stats(e, tid);

#pragma unroll 4
  for (int s = 0; s < 32; ++s) {
    int flat = tid + THREADS * s;
    int r = flat >> 7, j = flat & 127;
    int row = row0 + r;
    if (row < Nn) {
      float x = e.Cs[r][j];
      out[(size_t)row * 128 + j] =
          (x - e.mu[r]) * e.rs[r] * gf[j] + blf[j];
    }
  }
}

extern "C" void kernel_launch(void* const* d_in, const int* in_sizes, int n_in,
                              void* d_out, int out_size, void* d_ws, size_t ws_size,
                              hipStream_t stream) {
  const float* nodes = (const float*)d_in[0];
  const int* eidx    = (const int*)d_in[1];
  const float* eattr = (const float*)d_in[2];
  const float* Wm    = (const float*)d_in[3];
  const float* Wn    = (const float*)d_in[4];
  const float* W1    = (const float*)d_in[5];
  const float* b1    = (const float*)d_in[6];
  const float* g1    = (const float*)d_in[7];
  const float* bl1   = (const float*)d_in[8];
  const float* W2    = (const float*)d_in[9];
  const float* b2    = (const float*)d_in[10];
  const float* g2    = (const float*)d_in[11];
  const float* bl2   = (const float*)d_in[12];
  const float* gf    = (const float*)d_in[13];
  const float* blf   = (const float*)d_in[14];
  float* out = (float*)d_out;

  const int Nn = in_sizes[0] / 128;   // 100000
  const int E  = in_sizes[2] / 32;    // 800000

  // workspace layout (all 16B-aligned)
  int* counts  = (int*)d_ws;                       // [Nn]
  int* row_ptr = counts + Nn;                      // [Nn]
  int* cursor  = row_ptr + Nn;                     // [Nn] (segment ends after build)
  int* bsum    = cursor + Nn;                      // [256]
  int* boff    = bsum + 256;                       // [256]
  int* perm    = boff + 256;                       // [E]
  int* snds    = perm + E;                         // [E]
  unsigned short* Wcat     = (unsigned short*)(snds + E);       // [128*288]
  unsigned short* W2b      = Wcat + 128 * 288;                  // [128*128]
  unsigned short* Wnb      = W2b + 128 * 128;                   // [128*128]
  unsigned short* nodes_bf = Wnb + 128 * 128;                   // [Nn*128]
  unsigned short* h_bf     = nodes_bf + (size_t)Nn * 128;       // [Nn*128]
  unsigned short* S_bf     = h_bf + (size_t)Nn * 128;           // [Nn*160]

  hipMemsetAsync(counts, 0, (size_t)Nn * sizeof(int), stream);

  const int nconv = (Nn * 32 + 255) / 256;   // nodes float4 chunks
  const int nhist = (E + 255) / 256;
  const int NB = (Nn + 2047) / 2048;
  const int ngrid = (Nn + BM - 1) / BM;

  prep_kernel<<<160 + nconv + nhist, 256, 0, stream>>>(
      W1, Wm, W2, Wn, nodes, eidx, Wcat, W2b, Wnb, nodes_bf, counts, Nn, E, nconv);
  scan1_kernel<<<NB, 256, 0, stream>>>(counts, bsum, Nn);
  scan2_kernel<<<1, 256, 0, stream>>>(bsum, boff, NB);
  scan3_kernel<<<NB, 256, 0, stream>>>(counts, boff, row_ptr, cursor, Nn);
  build_kernel<<<nhist, 256, 0, stream>>>(eidx, cursor, perm, snds, E);
  aggsum_kernel<<<(Nn + 3) / 4, 256, 0, stream>>>(nodes_bf, eattr, row_ptr, cursor,
                                                  perm, snds, S_bf, Nn);
  node0_kernel<<<ngrid, THREADS, 0, stream>>>(nodes_bf, S_bf, Wcat, b1, g1, bl1,
                                              h_bf, Nn);
  node12_kernel<<<ngrid, THREADS, 0, stream>>>(h_bf, nodes_bf, W2b, Wnb, b2, g2,
                                               bl2, gf, blf, out, Nn);
}